// Round 3
// baseline (1829.213 us; speedup 1.0000x reference)
//
#include <hip/hip_runtime.h>
#include <hip/hip_bf16.h>
#include <math.h>

// Problem constants
#define D_MODEL 2048
#define D_FF    8192
#define MTOK    8192        // 4*2048 tokens
#define GSIZE   64
#define QBF     127.0f
#define EPSQ    1e-5f
#define W_NUMEL (D_FF * D_MODEL)        // 16,777,216 per weight
#define W_INV_NUMEL (1.0f / 16777216.0f)
#define NWAVE_PACK (W_NUMEL / 8 / 64)   // 32768 waves per wpack dispatch

typedef unsigned short u16;
typedef unsigned char  u8;
typedef unsigned int   u32;
typedef __attribute__((ext_vector_type(4))) float f32x4;
typedef __attribute__((ext_vector_type(4))) int   i32x4;
typedef __attribute__((ext_vector_type(4))) unsigned int u32x4;

// Async global->LDS, 16B per lane. LDS image must be linear in lane order.
__device__ __forceinline__ void gload_lds16(const void* g, void* l) {
    __builtin_amdgcn_global_load_lds(
        (const __attribute__((address_space(1))) unsigned int*)g,
        (__attribute__((address_space(3))) unsigned int*)l, 16, 0, 0);
}

// Bijective XCD-chunked block swizzle (m204).
__device__ __forceinline__ void xcd_swizzle(int& bx, int& by, int gx, int gy) {
    int nwg  = gx * gy;
    int orig = by * gx + bx;
    int q = nwg >> 3, r = nwg & 7;
    int xcd = orig & 7, loc = orig >> 3;
    int swz = (xcd < r ? xcd * (q + 1) : r * (q + 1) + (xcd - r) * q) + loc;
    bx = swz % gx;
    by = swz / gx;
}

// ---- int8 tile layout -------------------------------------------------
// 128 rows x 64 k x 1 B = 8 KB contiguous tile. Row = 64 B = 4 chunks of
// 16 B. Chunk swizzle c' = c ^ ((row>>1)&3): per-quad ds_read_b128 of
// 16 rows spreads across bank halves (row&1) x 4 chunk-slots -> balanced
// 8-access/bank = the b128 inherent minimum (conflict-free).
// Element (tile t, row r, k): off = t*8192 + r*64 + ((((k>>4)&3)^((r>>1)&3))<<4) + (k&15)

// ------- weight pack: fp32 [N,K] -> {-1,0,1} int8 swizzled tiles ---------
// Per-wave |w| partials to scratch (contention-free), reduced separately.
__global__ void wpack_kernel(const float* __restrict__ W, u8* __restrict__ Wb,
                             float* __restrict__ partial, int N, int K) {
    const int Gk  = K >> 6;
    const int cpr = K >> 3;                 // 8-elem chunks per row
    int idx = blockIdx.x * blockDim.x + threadIdx.x;   // grid is exact
    int row = idx / cpr;
    int ck  = idx - row * cpr;
    int k0  = ck << 3;
    const float* src = W + (size_t)row * K + k0;
    f32x4 w0 = *(const f32x4*)src;
    f32x4 w1 = *(const f32x4*)(src + 4);
    float s = 0.f;
    unsigned long long pk = 0ull;
    #pragma unroll
    for (int i = 0; i < 8; ++i) {
        float wv = (i < 4) ? w0[i] : w1[i - 4];
        s += fabsf(wv);
        int sv = (wv > 0.f) ? 1 : ((wv < 0.f) ? -1 : 0);
        pk |= ((unsigned long long)(u8)(signed char)sv) << (8 * i);
    }
    int nt = row >> 7, r = row & 127;
    int g = k0 >> 6, c = (k0 & 63) >> 4, j = k0 & 15;   // j in {0,8}
    size_t dst = ((size_t)(nt * Gk + g) << 13) + (size_t)r * 64
               + (size_t)((c ^ ((r >> 1) & 3)) << 4) + j;
    *(unsigned long long*)(Wb + dst) = pk;
    #pragma unroll
    for (int off = 32; off > 0; off >>= 1) s += __shfl_xor(s, off);
    if ((threadIdx.x & 63) == 0) partial[idx >> 6] = s;
}

// Sum 3 partial arrays -> wsum[0..2]. Grid = 3 blocks of 256.
__global__ void wsum_reduce(const float* __restrict__ partial, float* __restrict__ wsum) {
    __shared__ float red[4];
    const float* p = partial + (size_t)blockIdx.x * NWAVE_PACK;
    float s = 0.f;
    for (int i = threadIdx.x; i < NWAVE_PACK; i += 256) s += p[i];
    #pragma unroll
    for (int off = 32; off > 0; off >>= 1) s += __shfl_xor(s, off);
    if ((threadIdx.x & 63) == 0) red[threadIdx.x >> 6] = s;
    __syncthreads();
    if (threadIdx.x == 0) wsum[blockIdx.x] = red[0] + red[1] + red[2] + red[3];
}

// ---------------- per-group activation quant -> int8 swizzled tiles ------
__global__ void quant_kernel(const float* __restrict__ X, u8* __restrict__ Q,
                             float* __restrict__ SdivT, int M, int Gk) {
    const int K = Gk << 6;
    const int lane = threadIdx.x & 63;
    const int segs = K >> 8;
    int widx = (blockIdx.x * blockDim.x + threadIdx.x) >> 6;
    if (widx >= M * segs) return;
    int row = widx / segs;
    int seg = widx - row * segs;
    int k0 = (seg << 8) + lane * 4;
    f32x4 v = *(const f32x4*)(X + (size_t)row * K + k0);
    float a = fmaxf(fmaxf(fabsf(v[0]), fabsf(v[1])), fmaxf(fabsf(v[2]), fabsf(v[3])));
    a = fmaxf(a, __shfl_xor(a, 1));
    a = fmaxf(a, __shfl_xor(a, 2));
    a = fmaxf(a, __shfl_xor(a, 4));
    a = fmaxf(a, __shfl_xor(a, 8));          // max over 16-lane (64-elem) group
    float s = fmaxf(a, EPSQ);
    float rinv = QBF / s;
    u32 pk = 0;
    #pragma unroll
    for (int c = 0; c < 4; ++c) {
        float q = rintf(fminf(fmaxf(v[c] * rinv, -QBF), QBF));
        pk |= ((u32)(u8)(signed char)(int)q) << (8 * c);
    }
    int mt = row >> 7, r = row & 127;
    int gi = k0 >> 6;
    int c8 = (k0 & 63) >> 4, j0 = k0 & 15;   // j0 in {0,4,8,12}
    size_t dst = ((size_t)(mt * Gk + gi) << 13) + (size_t)r * 64
               + (size_t)((c8 ^ ((r >> 1) & 3)) << 4) + j0;
    *(u32*)(Q + dst) = pk;
    if ((lane & 15) == 0) SdivT[(size_t)gi * M + row] = s / QBF;
}

// ------------- fused up-projection: GEMM1+GEMM2 + silu*mul + requant -----
// int8 MFMA (16x16x64), double-buffered LDS, prefetch-before-compute.
__global__ __launch_bounds__(256, 3)
void gemm_bit12(const u8* __restrict__ Aq, const float* __restrict__ SdivT,
                const u8* __restrict__ W1b, const u8* __restrict__ W2b,
                const float* __restrict__ wsum,
                u8* __restrict__ Qh, float* __restrict__ ShT,
                int G, int Mtot) {
    __shared__ __align__(16) u8 lsm[2][3][8192];   // dbuf x {A,B1,B2}; 48 KB

    const int tid  = threadIdx.x;
    const int lane = tid & 63;
    const int wid  = tid >> 6;
    const int quad = lane >> 4;
    const int l16  = lane & 15;
    const int wm = (wid & 1) * 64;
    const int wn = (wid >> 1) * 64;

    int bx = blockIdx.x, by = blockIdx.y;
    xcd_swizzle(bx, by, gridDim.x, gridDim.y);
    const int m0 = by * 128;

    const u8* gA  = Aq  + ((size_t)by * G << 13);
    const u8* gB1 = W1b + ((size_t)bx * G << 13);
    const u8* gB2 = W2b + ((size_t)bx * G << 13);
    const int srow = m0 + wm + (quad << 2);        // sf rows: srow + mi*16 + 0..3

    f32x4 acc1[4][4], acc2[4][4];
    #pragma unroll
    for (int i = 0; i < 4; ++i)
        #pragma unroll
        for (int j = 0; j < 4; ++j) {
            acc1[i][j] = (f32x4){0.f, 0.f, 0.f, 0.f};
            acc2[i][j] = (f32x4){0.f, 0.f, 0.f, 0.f};
        }
    const i32x4 izero = {0, 0, 0, 0};
    f32x4 sfc[4], sfn[4];

    // ---- prologue: stage g=0 into buf0, load its scales ----
    {
        const u8* sA  = gA;  const u8* sB1 = gB1; const u8* sB2 = gB2;
        gload_lds16(sA  + tid * 16,        &lsm[0][0][tid * 16]);
        gload_lds16(sA  + 4096 + tid * 16, &lsm[0][0][4096 + tid * 16]);
        gload_lds16(sB1 + tid * 16,        &lsm[0][1][tid * 16]);
        gload_lds16(sB1 + 4096 + tid * 16, &lsm[0][1][4096 + tid * 16]);
        gload_lds16(sB2 + tid * 16,        &lsm[0][2][tid * 16]);
        gload_lds16(sB2 + 4096 + tid * 16, &lsm[0][2][4096 + tid * 16]);
        const float* sp = SdivT + srow;
        #pragma unroll
        for (int mi = 0; mi < 4; ++mi) sfc[mi] = *(const f32x4*)(sp + mi * 16);
        #pragma unroll
        for (int mi = 0; mi < 4; ++mi) sfn[mi] = sfc[mi];
    }
    __syncthreads();

    int cur = 0;
    for (int g = 0; g < G; ++g) {
        // ---- prefetch next K-tile BEFORE compute (loads fly under MFMA) ----
        if (g + 1 < G) {
            int nb = cur ^ 1;
            const u8* sA  = gA  + ((size_t)(g + 1) << 13);
            const u8* sB1 = gB1 + ((size_t)(g + 1) << 13);
            const u8* sB2 = gB2 + ((size_t)(g + 1) << 13);
            gload_lds16(sA  + tid * 16,        &lsm[nb][0][tid * 16]);
            gload_lds16(sA  + 4096 + tid * 16, &lsm[nb][0][4096 + tid * 16]);
            gload_lds16(sB1 + tid * 16,        &lsm[nb][1][tid * 16]);
            gload_lds16(sB1 + 4096 + tid * 16, &lsm[nb][1][4096 + tid * 16]);
            gload_lds16(sB2 + tid * 16,        &lsm[nb][2][tid * 16]);
            gload_lds16(sB2 + 4096 + tid * 16, &lsm[nb][2][4096 + tid * 16]);
            const float* sp = SdivT + (size_t)(g + 1) * Mtot + srow;
            #pragma unroll
            for (int mi = 0; mi < 4; ++mi) sfn[mi] = *(const f32x4*)(sp + mi * 16);
        }

        // ---- compute on current buffer ----
        const u8* LA  = &lsm[cur][0][0];
        const u8* LB1 = &lsm[cur][1][0];
        const u8* LB2 = &lsm[cur][2][0];
        i32x4 av[4];
        #pragma unroll
        for (int mi = 0; mi < 4; ++mi) {
            int r = wm + mi * 16 + l16;
            av[mi] = *(const i32x4*)(LA + r * 64 + ((quad ^ ((r >> 1) & 3)) << 4));
        }
        #pragma unroll
        for (int ni = 0; ni < 4; ++ni) {
            int rb = wn + ni * 16 + l16;
            int sw = (quad ^ ((rb >> 1) & 3)) << 4;
            i32x4 bv1 = *(const i32x4*)(LB1 + rb * 64 + sw);
            i32x4 bv2 = *(const i32x4*)(LB2 + rb * 64 + sw);
            #pragma unroll
            for (int mi = 0; mi < 4; ++mi) {
                i32x4 d1 = __builtin_amdgcn_mfma_i32_16x16x64_i8(av[mi], bv1, izero, 0, 0, 0);
                i32x4 d2 = __builtin_amdgcn_mfma_i32_16x16x64_i8(av[mi], bv2, izero, 0, 0, 0);
                f32x4 f1 = {(float)d1[0], (float)d1[1], (float)d1[2], (float)d1[3]};
                f32x4 f2 = {(float)d2[0], (float)d2[1], (float)d2[2], (float)d2[3]};
                acc1[mi][ni] += f1 * sfc[mi];
                acc2[mi][ni] += f2 * sfc[mi];
            }
        }
        __syncthreads();     // drains prefetch (had full compute phase to land)
        cur ^= 1;
        #pragma unroll
        for (int mi = 0; mi < 4; ++mi) sfc[mi] = sfn[mi];
    }

    // ---- epilogue: h = silu(y1)*y2, per-64-group int8 quant, tile out ----
    const float ws1 = wsum[0] * W_INV_NUMEL;
    const float ws2 = wsum[1] * W_INV_NUMEL;
    const int gl    = wn >> 6;                 // which of the 2 groups in this block
    const int gbase = bx * 2;                  // global d_ff group base
    u8* stg = &lsm[0][0][0];                   // 16 KB staging (loop ended w/ barrier)
    #pragma unroll
    for (int mi = 0; mi < 4; ++mi) {
        #pragma unroll
        for (int rr = 0; rr < 4; ++rr) {
            float h[4];
            #pragma unroll
            for (int ni = 0; ni < 4; ++ni) {
                float y1 = acc1[mi][ni][rr] * ws1;
                float y2 = acc2[mi][ni][rr] * ws2;
                h[ni] = (y1 / (1.f + expf(-y1))) * y2;   // silu(y1)*y2
            }
            float am = fmaxf(fmaxf(fabsf(h[0]), fabsf(h[1])), fmaxf(fabsf(h[2]), fabsf(h[3])));
            am = fmaxf(am, __shfl_xor(am, 1));
            am = fmaxf(am, __shfl_xor(am, 2));
            am = fmaxf(am, __shfl_xor(am, 4));
            am = fmaxf(am, __shfl_xor(am, 8));   // absmax over 4 ni x 16 lanes = 64 cols
            float s = fmaxf(am, EPSQ);
            float rinv = QBF / s;
            int rblk = wm + mi * 16 + quad * 4 + rr;
            #pragma unroll
            for (int ni = 0; ni < 4; ++ni) {
                float qv = rintf(fminf(fmaxf(h[ni] * rinv, -QBF), QBF));
                int k = ni * 16 + l16;
                stg[gl * 8192 + rblk * 64 + ((ni ^ ((rblk >> 1) & 3)) << 4) + l16]
                    = (u8)(signed char)(int)qv;
                (void)k;
            }
            if (l16 == 0) ShT[(size_t)(gbase + gl) * Mtot + m0 + rblk] = s / QBF;
        }
    }
    __syncthreads();
    // two 8 KB tiles (groups gbase, gbase+1) are contiguous in Qh
    size_t base = ((size_t)by * 128 + (size_t)gbase) << 13;   // bytes; Gff=128
    u32x4* dst = (u32x4*)(Qh + base);
    const u32x4* src = (const u32x4*)stg;
    #pragma unroll
    for (int i = 0; i < 4; ++i) dst[tid + i * 256] = src[tid + i * 256];
}

// ---------------- down-projection: (split-K) int8 bit-GEMM ---------------
// gridDim.z == 1 -> plain stores; > 1 -> fp32 atomicAdd onto zeroed output.
__global__ __launch_bounds__(256, 4)
void gemm_bit3(const u8* __restrict__ Aq, const float* __restrict__ SdivT,
               const u8* __restrict__ Wb, const float* __restrict__ wsum,
               float* __restrict__ Y, int N, int G, int Mtot, int gPer) {
    __shared__ __align__(16) u8 lsm[2][2][8192];   // dbuf x {A,B}; 32 KB

    const int tid  = threadIdx.x;
    const int lane = tid & 63;
    const int wid  = tid >> 6;
    const int quad = lane >> 4;
    const int l16  = lane & 15;
    const int wm = (wid & 1) * 64;
    const int wn = (wid >> 1) * 64;

    int bx = blockIdx.x, by = blockIdx.y;
    xcd_swizzle(bx, by, gridDim.x, gridDim.y);
    const int m0 = by * 128;
    const int n0 = bx * 128;
    const int g0 = blockIdx.z * gPer;

    const u8* gA = Aq + ((size_t)by * G << 13);
    const u8* gB = Wb + ((size_t)bx * G << 13);
    const int srow = m0 + wm + (quad << 2);

    f32x4 acc[4][4];
    #pragma unroll
    for (int i = 0; i < 4; ++i)
        #pragma unroll
        for (int j = 0; j < 4; ++j) acc[i][j] = (f32x4){0.f, 0.f, 0.f, 0.f};
    const i32x4 izero = {0, 0, 0, 0};
    f32x4 sfc[4], sfn[4];

    {
        const u8* sA = gA + ((size_t)g0 << 13);
        const u8* sB = gB + ((size_t)g0 << 13);
        gload_lds16(sA + tid * 16,        &lsm[0][0][tid * 16]);
        gload_lds16(sA + 4096 + tid * 16, &lsm[0][0][4096 + tid * 16]);
        gload_lds16(sB + tid * 16,        &lsm[0][1][tid * 16]);
        gload_lds16(sB + 4096 + tid * 16, &lsm[0][1][4096 + tid * 16]);
        const float* sp = SdivT + (size_t)g0 * Mtot + srow;
        #pragma unroll
        for (int mi = 0; mi < 4; ++mi) sfc[mi] = *(const f32x4*)(sp + mi * 16);
        #pragma unroll
        for (int mi = 0; mi < 4; ++mi) sfn[mi] = sfc[mi];
    }
    __syncthreads();

    int cur = 0;
    for (int g = g0; g < g0 + gPer; ++g) {
        if (g + 1 < g0 + gPer) {
            int nb = cur ^ 1;
            const u8* sA = gA + ((size_t)(g + 1) << 13);
            const u8* sB = gB + ((size_t)(g + 1) << 13);
            gload_lds16(sA + tid * 16,        &lsm[nb][0][tid * 16]);
            gload_lds16(sA + 4096 + tid * 16, &lsm[nb][0][4096 + tid * 16]);
            gload_lds16(sB + tid * 16,        &lsm[nb][1][tid * 16]);
            gload_lds16(sB + 4096 + tid * 16, &lsm[nb][1][4096 + tid * 16]);
            const float* sp = SdivT + (size_t)(g + 1) * Mtot + srow;
            #pragma unroll
            for (int mi = 0; mi < 4; ++mi) sfn[mi] = *(const f32x4*)(sp + mi * 16);
        }

        const u8* LA = &lsm[cur][0][0];
        const u8* LB = &lsm[cur][1][0];
        i32x4 av[4];
        #pragma unroll
        for (int mi = 0; mi < 4; ++mi) {
            int r = wm + mi * 16 + l16;
            av[mi] = *(const i32x4*)(LA + r * 64 + ((quad ^ ((r >> 1) & 3)) << 4));
        }
        #pragma unroll
        for (int ni = 0; ni < 4; ++ni) {
            int rb = wn + ni * 16 + l16;
            int sw = (quad ^ ((rb >> 1) & 3)) << 4;
            i32x4 bv = *(const i32x4*)(LB + rb * 64 + sw);
            #pragma unroll
            for (int mi = 0; mi < 4; ++mi) {
                i32x4 d = __builtin_amdgcn_mfma_i32_16x16x64_i8(av[mi], bv, izero, 0, 0, 0);
                f32x4 f = {(float)d[0], (float)d[1], (float)d[2], (float)d[3]};
                acc[mi][ni] += f * sfc[mi];
            }
        }
        __syncthreads();
        cur ^= 1;
        #pragma unroll
        for (int mi = 0; mi < 4; ++mi) sfc[mi] = sfn[mi];
    }

    const float wsc = wsum[0] * W_INV_NUMEL;   // mean|w3| (pre-offset by caller)
    #pragma unroll
    for (int mi = 0; mi < 4; ++mi) {
        #pragma unroll
        for (int ni = 0; ni < 4; ++ni) {
            int col = n0 + wn + ni * 16 + l16;
            #pragma unroll
            for (int r = 0; r < 4; ++r) {
                int row = m0 + wm + mi * 16 + quad * 4 + r;
                size_t o = (size_t)row * N + col;
                float v = acc[mi][ni][r] * wsc;
                if (gridDim.z == 1) Y[o] = v;
                else atomicAdd(&Y[o], v);
            }
        }
    }
}

extern "C" void kernel_launch(void* const* d_in, const int* in_sizes, int n_in,
                              void* d_out, int out_size, void* d_ws, size_t ws_size,
                              hipStream_t stream) {
    const float* x  = (const float*)d_in[0];
    const float* w1 = (const float*)d_in[1];
    const float* w2 = (const float*)d_in[2];
    const float* w3 = (const float*)d_in[3];
    float* out = (float*)d_out;

    // ---- workspace: packed int8 weights (fixed) + chunked activations ----
    char* ws = (char*)d_ws;
    const size_t wbBytes = (size_t)W_NUMEL;            // 16 MB per packed weight
    float* wsum = (float*)ws;
    char* p = ws + 256;
    u8* w1b = (u8*)p;  p += wbBytes;
    u8* w2b = (u8*)p;  p += wbBytes;
    u8* w3b = (u8*)p;  p += wbBytes;
    float* partial = (float*)p;  p += (size_t)3 * NWAVE_PACK * 4;   // 384 KB
    size_t fixed = (size_t)(p - ws);

    // per-token: qx 2048 + sxT 128 + qh 8192 + shT 512 = 10,880 B
    const size_t perTok = (size_t)D_MODEL + 32 * 4 + (size_t)D_FF + 128 * 4;
    int Mc = 1024;
    for (int cand = MTOK; cand >= 1024; cand >>= 1) {
        if (fixed + perTok * (size_t)cand <= ws_size) { Mc = cand; break; }
    }
    const int nChunks = MTOK / Mc;

    u8*    qx  = (u8*)p;          p += (size_t)Mc * D_MODEL;
    float* sxT = (float*)p;       p += (size_t)Mc * 32 * 4;      // [32][Mc]
    u8*    qh  = (u8*)p;          p += (size_t)Mc * D_FF;
    float* shT = (float*)p;                                      // [128][Mc]

    // pack weights + contention-free |w| partials (weights read exactly once)
    wpack_kernel<<<W_NUMEL / 8 / 256, 256, 0, stream>>>(w1, w1b, partial + 0 * NWAVE_PACK, D_FF, D_MODEL);
    wpack_kernel<<<W_NUMEL / 8 / 256, 256, 0, stream>>>(w2, w2b, partial + 1 * NWAVE_PACK, D_FF, D_MODEL);
    wpack_kernel<<<W_NUMEL / 8 / 256, 256, 0, stream>>>(w3, w3b, partial + 2 * NWAVE_PACK, D_MODEL, D_FF);
    wsum_reduce<<<3, 256, 0, stream>>>(partial, wsum);

    const int S = MTOK / Mc;                    // split-K factor (1 when Mc=8192)
    const int gPer = (D_FF / GSIZE) / S;
    if (S > 1) (void)hipMemsetAsync(out, 0, (size_t)out_size, stream);

    for (int c = 0; c < nChunks; ++c) {
        const float* xc = x + (size_t)c * Mc * D_MODEL;
        float* outc     = out + (size_t)c * Mc * D_MODEL;

        quant_kernel<<<Mc * D_MODEL / 1024, 256, 0, stream>>>(xc, qx, sxT, Mc, D_MODEL / GSIZE);

        dim3 g12(D_FF / 128, Mc / 128);
        gemm_bit12<<<g12, 256, 0, stream>>>(qx, sxT, w1b, w2b, wsum, qh, shT,
                                            D_MODEL / GSIZE, Mc);

        dim3 g3(D_MODEL / 128, Mc / 128, S);
        gemm_bit3<<<g3, 256, 0, stream>>>(qh, shT, w3b, wsum + 2, outc,
                                          D_MODEL, D_FF / GSIZE, Mc, gPer);
    }
}

// Round 4
// 1047.935 us; speedup vs baseline: 1.7455x; 1.7455x over previous
//
#include <hip/hip_runtime.h>
#include <hip/hip_bf16.h>
#include <math.h>

// Problem constants
#define D_MODEL 2048
#define D_FF    8192
#define MTOK    8192        // 4*2048 tokens
#define GSIZE   64
#define QBF     127.0f
#define EPSQ    1e-5f
#define W_NUMEL (D_FF * D_MODEL)        // 16,777,216 per weight
#define W_INV_NUMEL (1.0f / 16777216.0f)
#define NWAVE_PACK (W_NUMEL / 8 / 64)   // 32768 waves per wpack dispatch

typedef unsigned short u16;
typedef unsigned char  u8;
typedef unsigned int   u32;
typedef __attribute__((ext_vector_type(4))) float f32x4;
typedef __attribute__((ext_vector_type(4))) int   i32x4;
typedef __attribute__((ext_vector_type(4))) unsigned int u32x4;

// Async global->LDS, 16B per lane. LDS image must be linear in lane order.
__device__ __forceinline__ void gload_lds16(const void* g, void* l) {
    __builtin_amdgcn_global_load_lds(
        (const __attribute__((address_space(1))) unsigned int*)g,
        (__attribute__((address_space(3))) unsigned int*)l, 16, 0, 0);
}

// Supertiled XCD swizzle. orig -> (bx,by) bijectively (needs gx%8==0,
// nwg%8==0). Logical id order is (bxt, by, bxi): bxi=bx&7 fastest, then
// by, then bxt=bx>>3. Each XCD's contiguous 1/8 range covers ONE 8-wide
// bx column across all by -> its L2 holds an 8-column B panel (4 MB for
// g12) while A streams. Round-3 FETCH showed per-XCD full-B refetch per
// by-row (2.1 GB); this cuts it ~8x.
__device__ __forceinline__ void xcd_swizzle(int& bx, int& by, int gx, int gy) {
    int nwg  = gx * gy;
    int orig = by * gx + bx;
    int q = nwg >> 3;
    int xcd = orig & 7, loc = orig >> 3;
    int swz = xcd * q + loc;
    int bxi = swz & 7;
    int t   = swz >> 3;
    by = t % gy;
    bx = ((t / gy) << 3) + bxi;
}

// ---- int8 tile layout -------------------------------------------------
// 128 rows x 64 k x 1 B = 8 KB contiguous tile. Row = 64 B = 4 chunks of
// 16 B. Chunk swizzle c' = c ^ ((row>>1)&3) balances banks for the
// per-quad ds_read_b128 fragment loads.
// Element (tile t, row r, k): off = t*8192 + r*64 + ((((k>>4)&3)^((r>>1)&3))<<4) + (k&15)

// ------- weight pack: fp32 [N,K] -> {-1,0,1} int8 swizzled tiles ---------
// Per-wave |w| partials to scratch (contention-free), reduced separately.
__global__ void wpack_kernel(const float* __restrict__ W, u8* __restrict__ Wb,
                             float* __restrict__ partial, int N, int K) {
    const int Gk  = K >> 6;
    const int cpr = K >> 3;                 // 8-elem chunks per row
    int idx = blockIdx.x * blockDim.x + threadIdx.x;   // grid is exact
    int row = idx / cpr;
    int ck  = idx - row * cpr;
    int k0  = ck << 3;
    const float* src = W + (size_t)row * K + k0;
    f32x4 w0 = *(const f32x4*)src;
    f32x4 w1 = *(const f32x4*)(src + 4);
    float s = 0.f;
    unsigned long long pk = 0ull;
    #pragma unroll
    for (int i = 0; i < 8; ++i) {
        float wv = (i < 4) ? w0[i] : w1[i - 4];
        s += fabsf(wv);
        int sv = (wv > 0.f) ? 1 : ((wv < 0.f) ? -1 : 0);
        pk |= ((unsigned long long)(u8)(signed char)sv) << (8 * i);
    }
    int nt = row >> 7, r = row & 127;
    int g = k0 >> 6, c = (k0 & 63) >> 4, j = k0 & 15;   // j in {0,8}
    size_t dst = ((size_t)(nt * Gk + g) << 13) + (size_t)r * 64
               + (size_t)((c ^ ((r >> 1) & 3)) << 4) + j;
    *(unsigned long long*)(Wb + dst) = pk;
    #pragma unroll
    for (int off = 32; off > 0; off >>= 1) s += __shfl_xor(s, off);
    if ((threadIdx.x & 63) == 0) partial[idx >> 6] = s;
}

// Sum 3 partial arrays -> wsum[0..2]. Grid = 3 blocks of 256.
__global__ void wsum_reduce(const float* __restrict__ partial, float* __restrict__ wsum) {
    __shared__ float red[4];
    const float* p = partial + (size_t)blockIdx.x * NWAVE_PACK;
    float s = 0.f;
    for (int i = threadIdx.x; i < NWAVE_PACK; i += 256) s += p[i];
    #pragma unroll
    for (int off = 32; off > 0; off >>= 1) s += __shfl_xor(s, off);
    if ((threadIdx.x & 63) == 0) red[threadIdx.x >> 6] = s;
    __syncthreads();
    if (threadIdx.x == 0) wsum[blockIdx.x] = red[0] + red[1] + red[2] + red[3];
}

// ---------------- per-group activation quant -> int8 swizzled tiles ------
__global__ void quant_kernel(const float* __restrict__ X, u8* __restrict__ Q,
                             float* __restrict__ SdivT, int M, int Gk) {
    const int K = Gk << 6;
    const int lane = threadIdx.x & 63;
    const int segs = K >> 8;
    int widx = (blockIdx.x * blockDim.x + threadIdx.x) >> 6;
    if (widx >= M * segs) return;
    int row = widx / segs;
    int seg = widx - row * segs;
    int k0 = (seg << 8) + lane * 4;
    f32x4 v = *(const f32x4*)(X + (size_t)row * K + k0);
    float a = fmaxf(fmaxf(fabsf(v[0]), fabsf(v[1])), fmaxf(fabsf(v[2]), fabsf(v[3])));
    a = fmaxf(a, __shfl_xor(a, 1));
    a = fmaxf(a, __shfl_xor(a, 2));
    a = fmaxf(a, __shfl_xor(a, 4));
    a = fmaxf(a, __shfl_xor(a, 8));          // max over 16-lane (64-elem) group
    float s = fmaxf(a, EPSQ);
    float rinv = QBF / s;
    u32 pk = 0;
    #pragma unroll
    for (int c = 0; c < 4; ++c) {
        float q = rintf(fminf(fmaxf(v[c] * rinv, -QBF), QBF));
        pk |= ((u32)(u8)(signed char)(int)q) << (8 * c);
    }
    int mt = row >> 7, r = row & 127;
    int gi = k0 >> 6;
    int c8 = (k0 & 63) >> 4, j0 = k0 & 15;   // j0 in {0,4,8,12}
    size_t dst = ((size_t)(mt * Gk + gi) << 13) + (size_t)r * 64
               + (size_t)((c8 ^ ((r >> 1) & 3)) << 4) + j0;
    *(u32*)(Q + dst) = pk;
    if ((lane & 15) == 0) SdivT[(size_t)gi * M + row] = s / QBF;
}

// ------------- fused up-projection: GEMM1+GEMM2 + silu*mul + requant -----
// int8 MFMA (16x16x64), double-buffered LDS, prefetch-before-compute.
// launch_bounds(256,2): needs ~240 regs (acc 128 + temps); (256,3)'s
// 170-cap spilled acc -> 3.8 GB scratch writes in round 3.
__global__ __launch_bounds__(256, 2)
void gemm_bit12(const u8* __restrict__ Aq, const float* __restrict__ SdivT,
                const u8* __restrict__ W1b, const u8* __restrict__ W2b,
                const float* __restrict__ wsum,
                u8* __restrict__ Qh, float* __restrict__ ShT,
                int G, int Mtot) {
    __shared__ __align__(16) u8 lsm[2][3][8192];   // dbuf x {A,B1,B2}; 48 KB

    const int tid  = threadIdx.x;
    const int lane = tid & 63;
    const int wid  = tid >> 6;
    const int quad = lane >> 4;
    const int l16  = lane & 15;
    const int wm = (wid & 1) * 64;
    const int wn = (wid >> 1) * 64;

    int bx = blockIdx.x, by = blockIdx.y;
    xcd_swizzle(bx, by, gridDim.x, gridDim.y);
    const int m0 = by * 128;

    const u8* gA  = Aq  + ((size_t)by * G << 13);
    const u8* gB1 = W1b + ((size_t)bx * G << 13);
    const u8* gB2 = W2b + ((size_t)bx * G << 13);
    const int srow = m0 + wm + (quad << 2);        // sf rows: srow + mi*16 + 0..3

    f32x4 acc1[4][4], acc2[4][4];
    #pragma unroll
    for (int i = 0; i < 4; ++i)
        #pragma unroll
        for (int j = 0; j < 4; ++j) {
            acc1[i][j] = (f32x4){0.f, 0.f, 0.f, 0.f};
            acc2[i][j] = (f32x4){0.f, 0.f, 0.f, 0.f};
        }
    const i32x4 izero = {0, 0, 0, 0};
    f32x4 sfc[4], sfn[4];

    // ---- prologue: stage g=0 into buf0, load its scales ----
    {
        const u8* sA  = gA;  const u8* sB1 = gB1; const u8* sB2 = gB2;
        gload_lds16(sA  + tid * 16,        &lsm[0][0][tid * 16]);
        gload_lds16(sA  + 4096 + tid * 16, &lsm[0][0][4096 + tid * 16]);
        gload_lds16(sB1 + tid * 16,        &lsm[0][1][tid * 16]);
        gload_lds16(sB1 + 4096 + tid * 16, &lsm[0][1][4096 + tid * 16]);
        gload_lds16(sB2 + tid * 16,        &lsm[0][2][tid * 16]);
        gload_lds16(sB2 + 4096 + tid * 16, &lsm[0][2][4096 + tid * 16]);
        const float* sp = SdivT + srow;
        #pragma unroll
        for (int mi = 0; mi < 4; ++mi) sfc[mi] = *(const f32x4*)(sp + mi * 16);
        #pragma unroll
        for (int mi = 0; mi < 4; ++mi) sfn[mi] = sfc[mi];
    }
    __syncthreads();

    int cur = 0;
    for (int g = 0; g < G; ++g) {
        // ---- prefetch next K-tile BEFORE compute (loads fly under MFMA) ----
        if (g + 1 < G) {
            int nb = cur ^ 1;
            const u8* sA  = gA  + ((size_t)(g + 1) << 13);
            const u8* sB1 = gB1 + ((size_t)(g + 1) << 13);
            const u8* sB2 = gB2 + ((size_t)(g + 1) << 13);
            gload_lds16(sA  + tid * 16,        &lsm[nb][0][tid * 16]);
            gload_lds16(sA  + 4096 + tid * 16, &lsm[nb][0][4096 + tid * 16]);
            gload_lds16(sB1 + tid * 16,        &lsm[nb][1][tid * 16]);
            gload_lds16(sB1 + 4096 + tid * 16, &lsm[nb][1][4096 + tid * 16]);
            gload_lds16(sB2 + tid * 16,        &lsm[nb][2][tid * 16]);
            gload_lds16(sB2 + 4096 + tid * 16, &lsm[nb][2][4096 + tid * 16]);
            const float* sp = SdivT + (size_t)(g + 1) * Mtot + srow;
            #pragma unroll
            for (int mi = 0; mi < 4; ++mi) sfn[mi] = *(const f32x4*)(sp + mi * 16);
        }

        // ---- compute on current buffer ----
        const u8* LA  = &lsm[cur][0][0];
        const u8* LB1 = &lsm[cur][1][0];
        const u8* LB2 = &lsm[cur][2][0];
        i32x4 av[4];
        #pragma unroll
        for (int mi = 0; mi < 4; ++mi) {
            int r = wm + mi * 16 + l16;
            av[mi] = *(const i32x4*)(LA + r * 64 + ((quad ^ ((r >> 1) & 3)) << 4));
        }
        #pragma unroll
        for (int ni = 0; ni < 4; ++ni) {
            int rb = wn + ni * 16 + l16;
            int sw = (quad ^ ((rb >> 1) & 3)) << 4;
            i32x4 bv1 = *(const i32x4*)(LB1 + rb * 64 + sw);
            i32x4 bv2 = *(const i32x4*)(LB2 + rb * 64 + sw);
            #pragma unroll
            for (int mi = 0; mi < 4; ++mi) {
                i32x4 d1 = __builtin_amdgcn_mfma_i32_16x16x64_i8(av[mi], bv1, izero, 0, 0, 0);
                i32x4 d2 = __builtin_amdgcn_mfma_i32_16x16x64_i8(av[mi], bv2, izero, 0, 0, 0);
                f32x4 f1 = {(float)d1[0], (float)d1[1], (float)d1[2], (float)d1[3]};
                f32x4 f2 = {(float)d2[0], (float)d2[1], (float)d2[2], (float)d2[3]};
                acc1[mi][ni] += f1 * sfc[mi];
                acc2[mi][ni] += f2 * sfc[mi];
            }
        }
        __syncthreads();     // drains prefetch (had full compute phase to land)
        cur ^= 1;
        #pragma unroll
        for (int mi = 0; mi < 4; ++mi) sfc[mi] = sfn[mi];
    }

    // ---- epilogue: h = silu(y1)*y2, per-64-group int8 quant, tile out ----
    const float ws1 = wsum[0] * W_INV_NUMEL;
    const float ws2 = wsum[1] * W_INV_NUMEL;
    const int gl    = wn >> 6;                 // which of the 2 groups in this block
    const int gbase = bx * 2;                  // global d_ff group base
    u8* stg = &lsm[0][0][0];                   // 16 KB staging (loop ended w/ barrier)
    #pragma unroll
    for (int mi = 0; mi < 4; ++mi) {
        #pragma unroll
        for (int rr = 0; rr < 4; ++rr) {
            float h[4];
            #pragma unroll
            for (int ni = 0; ni < 4; ++ni) {
                float y1 = acc1[mi][ni][rr] * ws1;
                float y2 = acc2[mi][ni][rr] * ws2;
                h[ni] = (y1 / (1.f + expf(-y1))) * y2;   // silu(y1)*y2
            }
            float am = fmaxf(fmaxf(fabsf(h[0]), fabsf(h[1])), fmaxf(fabsf(h[2]), fabsf(h[3])));
            am = fmaxf(am, __shfl_xor(am, 1));
            am = fmaxf(am, __shfl_xor(am, 2));
            am = fmaxf(am, __shfl_xor(am, 4));
            am = fmaxf(am, __shfl_xor(am, 8));   // absmax over 4 ni x 16 lanes = 64 cols
            float s = fmaxf(am, EPSQ);
            float rinv = QBF / s;
            int rblk = wm + mi * 16 + quad * 4 + rr;
            #pragma unroll
            for (int ni = 0; ni < 4; ++ni) {
                float qv = rintf(fminf(fmaxf(h[ni] * rinv, -QBF), QBF));
                stg[gl * 8192 + rblk * 64 + ((ni ^ ((rblk >> 1) & 3)) << 4) + l16]
                    = (u8)(signed char)(int)qv;
            }
            if (l16 == 0) ShT[(size_t)(gbase + gl) * Mtot + m0 + rblk] = s / QBF;
        }
    }
    __syncthreads();
    // two 8 KB tiles (groups gbase, gbase+1) are contiguous in Qh
    size_t base = ((size_t)by * 128 + (size_t)gbase) << 13;   // bytes; Gff=128
    u32x4* dst = (u32x4*)(Qh + base);
    const u32x4* src = (const u32x4*)stg;
    #pragma unroll
    for (int i = 0; i < 4; ++i) dst[tid + i * 256] = src[tid + i * 256];
}

// ---------------- down-projection: (split-K) int8 bit-GEMM ---------------
// gridDim.z == 1 -> plain stores; > 1 -> fp32 atomicAdd onto zeroed output.
// launch_bounds(256,3): ~150 regs needed fits the 170 cap; (256,4)'s 128
// cap risked spill.
__global__ __launch_bounds__(256, 3)
void gemm_bit3(const u8* __restrict__ Aq, const float* __restrict__ SdivT,
               const u8* __restrict__ Wb, const float* __restrict__ wsum,
               float* __restrict__ Y, int N, int G, int Mtot, int gPer) {
    __shared__ __align__(16) u8 lsm[2][2][8192];   // dbuf x {A,B}; 32 KB

    const int tid  = threadIdx.x;
    const int lane = tid & 63;
    const int wid  = tid >> 6;
    const int quad = lane >> 4;
    const int l16  = lane & 15;
    const int wm = (wid & 1) * 64;
    const int wn = (wid >> 1) * 64;

    int bx = blockIdx.x, by = blockIdx.y;
    xcd_swizzle(bx, by, gridDim.x, gridDim.y);
    const int m0 = by * 128;
    const int n0 = bx * 128;
    const int g0 = blockIdx.z * gPer;

    const u8* gA = Aq + ((size_t)by * G << 13);
    const u8* gB = Wb + ((size_t)bx * G << 13);
    const int srow = m0 + wm + (quad << 2);

    f32x4 acc[4][4];
    #pragma unroll
    for (int i = 0; i < 4; ++i)
        #pragma unroll
        for (int j = 0; j < 4; ++j) acc[i][j] = (f32x4){0.f, 0.f, 0.f, 0.f};
    const i32x4 izero = {0, 0, 0, 0};
    f32x4 sfc[4], sfn[4];

    {
        const u8* sA = gA + ((size_t)g0 << 13);
        const u8* sB = gB + ((size_t)g0 << 13);
        gload_lds16(sA + tid * 16,        &lsm[0][0][tid * 16]);
        gload_lds16(sA + 4096 + tid * 16, &lsm[0][0][4096 + tid * 16]);
        gload_lds16(sB + tid * 16,        &lsm[0][1][tid * 16]);
        gload_lds16(sB + 4096 + tid * 16, &lsm[0][1][4096 + tid * 16]);
        const float* sp = SdivT + (size_t)g0 * Mtot + srow;
        #pragma unroll
        for (int mi = 0; mi < 4; ++mi) sfc[mi] = *(const f32x4*)(sp + mi * 16);
        #pragma unroll
        for (int mi = 0; mi < 4; ++mi) sfn[mi] = sfc[mi];
    }
    __syncthreads();

    int cur = 0;
    for (int g = g0; g < g0 + gPer; ++g) {
        if (g + 1 < g0 + gPer) {
            int nb = cur ^ 1;
            const u8* sA = gA + ((size_t)(g + 1) << 13);
            const u8* sB = gB + ((size_t)(g + 1) << 13);
            gload_lds16(sA + tid * 16,        &lsm[nb][0][tid * 16]);
            gload_lds16(sA + 4096 + tid * 16, &lsm[nb][0][4096 + tid * 16]);
            gload_lds16(sB + tid * 16,        &lsm[nb][1][tid * 16]);
            gload_lds16(sB + 4096 + tid * 16, &lsm[nb][1][4096 + tid * 16]);
            const float* sp = SdivT + (size_t)(g + 1) * Mtot + srow;
            #pragma unroll
            for (int mi = 0; mi < 4; ++mi) sfn[mi] = *(const f32x4*)(sp + mi * 16);
        }

        const u8* LA = &lsm[cur][0][0];
        const u8* LB = &lsm[cur][1][0];
        i32x4 av[4];
        #pragma unroll
        for (int mi = 0; mi < 4; ++mi) {
            int r = wm + mi * 16 + l16;
            av[mi] = *(const i32x4*)(LA + r * 64 + ((quad ^ ((r >> 1) & 3)) << 4));
        }
        #pragma unroll
        for (int ni = 0; ni < 4; ++ni) {
            int rb = wn + ni * 16 + l16;
            int sw = (quad ^ ((rb >> 1) & 3)) << 4;
            i32x4 bv = *(const i32x4*)(LB + rb * 64 + sw);
            #pragma unroll
            for (int mi = 0; mi < 4; ++mi) {
                i32x4 d = __builtin_amdgcn_mfma_i32_16x16x64_i8(av[mi], bv, izero, 0, 0, 0);
                f32x4 f = {(float)d[0], (float)d[1], (float)d[2], (float)d[3]};
                acc[mi][ni] += f * sfc[mi];
            }
        }
        __syncthreads();
        cur ^= 1;
        #pragma unroll
        for (int mi = 0; mi < 4; ++mi) sfc[mi] = sfn[mi];
    }

    const float wsc = wsum[0] * W_INV_NUMEL;   // mean|w3| (pre-offset by caller)
    #pragma unroll
    for (int mi = 0; mi < 4; ++mi) {
        #pragma unroll
        for (int ni = 0; ni < 4; ++ni) {
            int col = n0 + wn + ni * 16 + l16;
            #pragma unroll
            for (int r = 0; r < 4; ++r) {
                int row = m0 + wm + mi * 16 + quad * 4 + r;
                size_t o = (size_t)row * N + col;
                float v = acc[mi][ni][r] * wsc;
                if (gridDim.z == 1) Y[o] = v;
                else atomicAdd(&Y[o], v);
            }
        }
    }
}

extern "C" void kernel_launch(void* const* d_in, const int* in_sizes, int n_in,
                              void* d_out, int out_size, void* d_ws, size_t ws_size,
                              hipStream_t stream) {
    const float* x  = (const float*)d_in[0];
    const float* w1 = (const float*)d_in[1];
    const float* w2 = (const float*)d_in[2];
    const float* w3 = (const float*)d_in[3];
    float* out = (float*)d_out;

    // ---- workspace: packed int8 weights (fixed) + chunked activations ----
    char* ws = (char*)d_ws;
    const size_t wbBytes = (size_t)W_NUMEL;            // 16 MB per packed weight
    float* wsum = (float*)ws;
    char* p = ws + 256;
    u8* w1b = (u8*)p;  p += wbBytes;
    u8* w2b = (u8*)p;  p += wbBytes;
    u8* w3b = (u8*)p;  p += wbBytes;
    float* partial = (float*)p;  p += (size_t)3 * NWAVE_PACK * 4;   // 384 KB
    size_t fixed = (size_t)(p - ws);

    // per-token: qx 2048 + sxT 128 + qh 8192 + shT 512 = 10,880 B
    const size_t perTok = (size_t)D_MODEL + 32 * 4 + (size_t)D_FF + 128 * 4;
    int Mc = 1024;
    for (int cand = MTOK; cand >= 1024; cand >>= 1) {
        if (fixed + perTok * (size_t)cand <= ws_size) { Mc = cand; break; }
    }
    const int nChunks = MTOK / Mc;

    u8*    qx  = (u8*)p;          p += (size_t)Mc * D_MODEL;
    float* sxT = (float*)p;       p += (size_t)Mc * 32 * 4;      // [32][Mc]
    u8*    qh  = (u8*)p;          p += (size_t)Mc * D_FF;
    float* shT = (float*)p;                                      // [128][Mc]

    // pack weights + contention-free |w| partials (weights read exactly once)
    wpack_kernel<<<W_NUMEL / 8 / 256, 256, 0, stream>>>(w1, w1b, partial + 0 * NWAVE_PACK, D_FF, D_MODEL);
    wpack_kernel<<<W_NUMEL / 8 / 256, 256, 0, stream>>>(w2, w2b, partial + 1 * NWAVE_PACK, D_FF, D_MODEL);
    wpack_kernel<<<W_NUMEL / 8 / 256, 256, 0, stream>>>(w3, w3b, partial + 2 * NWAVE_PACK, D_MODEL, D_FF);
    wsum_reduce<<<3, 256, 0, stream>>>(partial, wsum);

    const int S = MTOK / Mc;                    // split-K factor (1 when Mc=8192)
    const int gPer = (D_FF / GSIZE) / S;
    if (S > 1) (void)hipMemsetAsync(out, 0, (size_t)out_size, stream);

    for (int c = 0; c < nChunks; ++c) {
        const float* xc = x + (size_t)c * Mc * D_MODEL;
        float* outc     = out + (size_t)c * Mc * D_MODEL;

        quant_kernel<<<Mc * D_MODEL / 1024, 256, 0, stream>>>(xc, qx, sxT, Mc, D_MODEL / GSIZE);

        dim3 g12(D_FF / 128, Mc / 128);
        gemm_bit12<<<g12, 256, 0, stream>>>(qx, sxT, w1b, w2b, wsum, qh, shT,
                                            D_MODEL / GSIZE, Mc);

        dim3 g3(D_MODEL / 128, Mc / 128, S);
        gemm_bit3<<<g3, 256, 0, stream>>>(qh, shT, w3b, wsum + 2, outc,
                                          D_MODEL, D_FF / GSIZE, Mc, gPer);
    }
}